// Round 2
// baseline (11.601 us; speedup 1.0000x reference)
//
#include <hip/hip_runtime.h>

#define NCOLS 1024
#define NROWS 32

// Single block, 16 waves. Wave w reduces rows 2w and 2w+1 fully in-register;
// wave 0 then averages the 32 row values. One graph node total.
__global__ __launch_bounds__(1024) void bpmll_fused_kernel(
    const float* __restrict__ c, const int* __restrict__ y,
    float* __restrict__ out) {
    const int tid = threadIdx.x;
    const int wave = tid >> 6;   // 0..15
    const int lane = tid & 63;
    __shared__ float rowv[NROWS];

    #pragma unroll
    for (int rr = 0; rr < 2; ++rr) {
        const int row = wave * 2 + rr;
        // c row is interleaved [c1_0, s1_0, c1_1, s1_1, ...]; float4 = 2 cols
        const float4* __restrict__ crow4 =
            reinterpret_cast<const float4*>(c + (size_t)row * 2 * NCOLS);
        const int2* __restrict__ yrow2 =
            reinterpret_cast<const int2*>(y + (size_t)row * NCOLS);

        float sy = 0.f, sA = 0.f, sB = 0.f, sC = 0.f, sD = 0.f;
        #pragma unroll
        for (int k = 0; k < 8; ++k) {
            const int idx = k * 64 + lane;
            const float4 F = crow4[idx];   // (c1, s1, c1', s1')
            const int2  Y = yrow2[idx];
            {   // element 2*idx
                const bool yy = (Y.x != 0);
                const float e1 = __expf(yy ? -F.x : F.x);  // exp(-c1) or exp(c1)
                const float e2 = __expf(yy ?  F.y : -F.y); // exp(s1) or exp(-s1)
                sy += yy ? 1.f : 0.f;
                sA += yy ? e1 : 0.f;
                sD += yy ? e2 : 0.f;
                sC += yy ? 0.f : e1;
                sB += yy ? 0.f : e2;
            }
            {   // element 2*idx+1
                const bool yy = (Y.y != 0);
                const float e1 = __expf(yy ? -F.z : F.z);
                const float e2 = __expf(yy ?  F.w : -F.w);
                sy += yy ? 1.f : 0.f;
                sA += yy ? e1 : 0.f;
                sD += yy ? e2 : 0.f;
                sC += yy ? 0.f : e1;
                sB += yy ? 0.f : e2;
            }
        }
        // full-wave butterfly reduce (5 sums)
        #pragma unroll
        for (int off = 32; off > 0; off >>= 1) {
            sy += __shfl_xor(sy, off);
            sA += __shfl_xor(sA, off);
            sB += __shfl_xor(sB, off);
            sC += __shfl_xor(sC, off);
            sD += __shfl_xor(sD, off);
        }
        if (lane == 0) {
            const float yn  = sy;
            const float ybn = (float)NCOLS - sy;
            const float denom = 2.f * yn * ybn + yn * yn + ybn * ybn;
            rowv[row] = (sA + sB) * (sC + sD) / denom;
        }
    }
    __syncthreads();
    if (tid < 64) {
        float v = (lane < NROWS) ? rowv[lane] : 0.f;
        #pragma unroll
        for (int off = 32; off > 0; off >>= 1) v += __shfl_xor(v, off);
        if (lane == 0) out[0] = v * (1.f / NROWS);
    }
}

extern "C" void kernel_launch(void* const* d_in, const int* in_sizes, int n_in,
                              void* d_out, int out_size, void* d_ws, size_t ws_size,
                              hipStream_t stream) {
    const float* c = (const float*)d_in[0];
    const int*   y = (const int*)d_in[1];
    float* out = (float*)d_out;
    (void)d_ws; (void)ws_size;
    bpmll_fused_kernel<<<1, 1024, 0, stream>>>(c, y, out);
}